// Round 9
// baseline (3606.428 us; speedup 1.0000x reference)
//
#include <hip/hip_runtime.h>
#include <hip/hip_bf16.h>
#include <hip/hip_fp16.h>
#include <cstdint>
#include <cstddef>

typedef __attribute__((ext_vector_type(4))) float floatx4;
typedef __attribute__((ext_vector_type(8))) short shortx8;
typedef __attribute__((ext_vector_type(2))) __fp16 f16x2;
typedef __attribute__((ext_vector_type(8))) __fp16 halfx8;

#define T_SEQ 512
#define NIN   512
#define BATCH 256
#define HID   256
#define G3    768
#define NC    101

static __device__ __forceinline__ unsigned short f2bf(float f){
  unsigned int u = __float_as_uint(f);
  u += 0x7FFFu + ((u >> 16) & 1u);
  return (unsigned short)(u >> 16);
}

// ---------------- Phase A: xg[gm][gn] = x . Wih^T + bih (+ bhh folded for
// r,z gates). Natural row-major fp16 output (gm = b*Tc+tt, gn = gate-col).
#define BM 128
#define BN 128
#define BK 64
#define LDK 72

__global__ __launch_bounds__(256) void gemm_xg(
    const float* __restrict__ x, const float* __restrict__ Wih,
    const float* __restrict__ bih, const float* __restrict__ bhh,
    __fp16* __restrict__ xg, int t0, int tcLog2)
{
  __shared__ unsigned short As[BM*LDK];
  __shared__ unsigned short Bs[BN*LDK];
  const int tid  = threadIdx.x;
  const int bn   = blockIdx.x;   // N fastest: 6 consecutive blocks share one x-tile (L2 reuse)
  const int bm   = blockIdx.y;
  const int w    = tid >> 6;
  const int l    = tid & 63;
  const int lm   = l & 15;
  const int quad = l >> 4;

  const int srow = tid >> 4;
  const int scol = (tid & 15) * 4;
  const int tcMask = (1 << tcLog2) - 1;

  floatx4 acc[2][8];
  #pragma unroll
  for (int mt = 0; mt < 2; ++mt)
    #pragma unroll
    for (int nt = 0; nt < 8; ++nt)
      acc[mt][nt] = (floatx4){0.f, 0.f, 0.f, 0.f};

  for (int kt = 0; kt < NIN / BK; ++kt){
    const int k0 = kt * BK;
    __syncthreads();
    #pragma unroll
    for (int p = 0; p < 8; ++p){
      const int r  = p * 16 + srow;
      const int gm = bm * BM + r;
      const int b  = gm >> tcLog2;
      const int tt = gm & tcMask;
      const float4 xa = *(const float4*)(x + (size_t)(b * T_SEQ + t0 + tt) * NIN + k0 + scol);
      union { unsigned short u[4]; uint2 v; } pa;
      pa.u[0] = f2bf(xa.x); pa.u[1] = f2bf(xa.y); pa.u[2] = f2bf(xa.z); pa.u[3] = f2bf(xa.w);
      *(uint2*)&As[r * LDK + scol] = pa.v;
      const int gn = bn * BN + r;
      const float4 wb = *(const float4*)(Wih + (size_t)gn * NIN + k0 + scol);
      union { unsigned short u[4]; uint2 v; } pb;
      pb.u[0] = f2bf(wb.x); pb.u[1] = f2bf(wb.y); pb.u[2] = f2bf(wb.z); pb.u[3] = f2bf(wb.w);
      *(uint2*)&Bs[r * LDK + scol] = pb.v;
    }
    __syncthreads();
    #pragma unroll
    for (int ks = 0; ks < 2; ++ks){
      const int kk = ks * 32 + quad * 8;
      shortx8 af[2], bfr[8];
      #pragma unroll
      for (int mt = 0; mt < 2; ++mt)
        af[mt] = *(const shortx8*)&As[(w * 32 + mt * 16 + lm) * LDK + kk];
      #pragma unroll
      for (int nt = 0; nt < 8; ++nt)
        bfr[nt] = *(const shortx8*)&Bs[(nt * 16 + lm) * LDK + kk];
      #pragma unroll
      for (int mt = 0; mt < 2; ++mt)
        #pragma unroll
        for (int nt = 0; nt < 8; ++nt)
          acc[mt][nt] = __builtin_amdgcn_mfma_f32_16x16x32_bf16(af[mt], bfr[nt], acc[mt][nt], 0, 0, 0);
    }
  }

  #pragma unroll
  for (int mt = 0; mt < 2; ++mt){
    #pragma unroll
    for (int nt = 0; nt < 8; ++nt){
      #pragma unroll
      for (int i = 0; i < 4; ++i){
        const int ml = w * 32 + mt * 16 + quad * 4 + i;
        const int nl = nt * 16 + lm;
        const int gm = bm * BM + ml;
        const int gn = bn * BN + nl;
        float v = acc[mt][nt][i] + bih[gn];
        if (gn < 512) v += bhh[gn];            // fold bhh for r,z gates (exact)
        xg[(size_t)gm * G3 + gn] = (__fp16)v;
      }
    }
  }
}

// ---------------- Phase B: batched-MFMA GRU, 1024 threads / 16 waves.
// Wave w owns j in [16w, 16w+16) for ALL 3 gates: 3 acc tiles of
// mfma_f32_16x16x32_f16 (M=16 batches, N=16 j, K=256 in 8 steps).
// B-frags (W_hh f16) = 3*8 halfx8 = 96 VGPRs/thread -> total arch demand
// ~125 <= the 128-reg cap at 4 waves/SIMD: no AGPR shuttling (R5/R7's
// failure was 192-reg Bf vs 128 cap). acc (12 f32) is MFMA-native AGPR.
// h: f32 state in regs; f16 mirror in LDS, double-buffered, XOR-swizzled.
// xg read as 12 scalar u16 loads/thread/step (issued early, L2/L3-hot).
#define BB 16

__global__ __launch_bounds__(1024, 1) void gru_mfma(
    const __fp16* __restrict__ xg, const float* __restrict__ Whh,
    const float* __restrict__ bhh, float* __restrict__ hstate, int Tc)
{
  __shared__ __align__(16) __fp16 hls[2][BB * HID];
  const int tid = threadIdx.x;
  const int w   = tid >> 6;        // wave 0..15: j-tile
  const int l   = tid & 63;
  const int lm  = l & 15;          // A row (batch) on reads; D col (j)
  const int lq  = l >> 4;          // k-chunk selector; D rows = lq*4+i
  const int bb0 = blockIdx.x * BB;
  const int j   = w * 16 + lm;     // this thread's j (0..255)
  const int hswz = (lm & 7) << 3;  // A-read swizzle (half units, keyed on A row)

  // B-frags: lane l holds W[g*256 + j][ks*32 + lq*8 .. +7] (f16) = 96 VGPRs
  halfx8 Bf[3][8];
  #pragma unroll
  for (int g = 0; g < 3; ++g)
    #pragma unroll
    for (int ks = 0; ks < 8; ++ks){
      const float* wp = Whh + (size_t)(g * 256 + j) * HID + ks * 32 + lq * 8;
      const float4 v0 = *(const float4*)wp;
      const float4 v1 = *(const float4*)(wp + 4);
      union { f16x2 h[4]; halfx8 v; } u;
      u.h[0] = __builtin_amdgcn_cvt_pkrtz(v0.x, v0.y);
      u.h[1] = __builtin_amdgcn_cvt_pkrtz(v0.z, v0.w);
      u.h[2] = __builtin_amdgcn_cvt_pkrtz(v1.x, v1.y);
      u.h[3] = __builtin_amdgcn_cvt_pkrtz(v1.z, v1.w);
      Bf[g][ks] = u.v;
    }

  // Only n-gate bhh lives here (r,z folded into xg by gemm_xg).
  const float bnv = bhh[512 + j];

  // init h (f32 state in regs + f16 mirror in LDS buf 0); each (b,j) written once
  float hold[4];
  #pragma unroll
  for (int i = 0; i < 4; ++i){
    const int b = lq * 4 + i;
    const float h0 = hstate[(bb0 + b) * HID + j];
    hold[i] = h0;
    hls[0][b * HID + (j ^ ((b & 7) << 3))] = (__fp16)h0;
  }

  // xg base pointers for this thread's 4 batch rows at column j
  const __fp16* xp0 = xg + ((size_t)(bb0 + lq * 4 + 0) * Tc) * G3 + j;
  const __fp16* xp1 = xg + ((size_t)(bb0 + lq * 4 + 1) * Tc) * G3 + j;
  const __fp16* xp2 = xg + ((size_t)(bb0 + lq * 4 + 2) * Tc) * G3 + j;
  const __fp16* xp3 = xg + ((size_t)(bb0 + lq * 4 + 3) * Tc) * G3 + j;

  __syncthreads();

  #pragma unroll 1
  for (int t = 0; t < Tc; ++t){
    // 12 scalar u16 loads: issued here, consumed after the MFMA loop
    __fp16 xr[4], xz[4], xn[4];
    xr[0] = xp0[0]; xz[0] = xp0[256]; xn[0] = xp0[512];
    xr[1] = xp1[0]; xz[1] = xp1[256]; xn[1] = xp1[512];
    xr[2] = xp2[0]; xz[2] = xp2[256]; xn[2] = xp2[512];
    xr[3] = xp3[0]; xz[3] = xp3[256]; xn[3] = xp3[512];

    floatx4 acc[3];
    #pragma unroll
    for (int g = 0; g < 3; ++g)
      acc[g] = (floatx4){0.f, 0.f, 0.f, 0.f};

    const __fp16* hb = &hls[t & 1][0];
    const __fp16* p0 = hb + lm * HID + ((lq * 8) ^ hswz);
    const __fp16* p1 = hb + lm * HID + ((32 + lq * 8) ^ hswz);
    #pragma unroll
    for (int ks = 0; ks < 8; ++ks){
      const halfx8 av = *(const halfx8*)(((ks & 1) ? p1 : p0) + (ks >> 1) * 64);
      #pragma unroll
      for (int g = 0; g < 3; ++g)
        acc[g] = __builtin_amdgcn_mfma_f32_16x16x32_f16(av, Bf[g][ks], acc[g], 0, 0, 0);
    }

    __fp16* hbn = &hls[(t + 1) & 1][0];
    #pragma unroll
    for (int i = 0; i < 4; ++i){
      const float r = 1.f / (1.f + __expf(-((float)xr[i] + acc[0][i])));
      const float z = 1.f / (1.f + __expf(-((float)xz[i] + acc[1][i])));
      const float a = (float)xn[i] + r * (acc[2][i] + bnv);
      const float ex = __expf(-2.f * fabsf(a));
      float n = (1.f - ex) / (1.f + ex);
      n = copysignf(n, a);
      const float hnew = fmaf(z, hold[i] - n, n);   // (1-z)*n + z*h
      hold[i] = hnew;
      const int b = lq * 4 + i;
      hbn[b * HID + (j ^ ((b & 7) << 3))] = (__fp16)hnew;
    }
    __syncthreads();
    xp0 += G3; xp1 += G3; xp2 += G3; xp3 += G3;
  }

  #pragma unroll
  for (int i = 0; i < 4; ++i)
    hstate[(bb0 + lq * 4 + i) * HID + j] = hold[i];
}

// ---------------- FC
__global__ __launch_bounds__(128) void fc_kernel(
    const float* __restrict__ hstate, const float* __restrict__ fw,
    const float* __restrict__ fb, float* __restrict__ out)
{
  __shared__ float hs[HID];
  const int b = blockIdx.x;
  const int t = threadIdx.x;
  hs[t]       = hstate[b * HID + t];
  hs[t + 128] = hstate[b * HID + t + 128];
  __syncthreads();
  if (t < NC){
    float acc = fb[t];
    const float4* w4 = (const float4*)(fw + (size_t)t * HID);
    const float4* h4 = (const float4*)hs;
    #pragma unroll
    for (int k = 0; k < 64; ++k){
      const float4 wv = w4[k];
      const float4 hv = h4[k];
      acc += wv.x * hv.x + wv.y * hv.y + wv.z * hv.z + wv.w * hv.w;
    }
    out[b * NC + t] = acc;
  }
}

extern "C" void kernel_launch(void* const* d_in, const int* in_sizes, int n_in,
                              void* d_out, int out_size, void* d_ws, size_t ws_size,
                              hipStream_t stream)
{
  const float* x   = (const float*)d_in[0];
  const float* Wih = (const float*)d_in[1];
  const float* Whh = (const float*)d_in[2];
  const float* bih = (const float*)d_in[3];
  const float* bhh = (const float*)d_in[4];
  const float* fcw = (const float*)d_in[5];
  const float* fcb = (const float*)d_in[6];
  float* out = (float*)d_out;

  float* hst = (float*)d_ws;
  const size_t hBytes = (size_t)BATCH * HID * sizeof(float);
  __fp16* xg = (__fp16*)((char*)d_ws + hBytes);

  const size_t perT = (size_t)BATCH * G3 * sizeof(__fp16);
  const size_t avail = (ws_size > hBytes) ? (ws_size - hBytes) : 0;
  int tcLog2 = 9;
  while (tcLog2 > 0 && perT * ((size_t)1 << tcLog2) > avail) --tcLog2;
  const int Tc = 1 << tcLog2;

  (void)hipMemsetAsync(hst, 0, hBytes, stream);
  for (int t0 = 0; t0 < T_SEQ; t0 += Tc){
    dim3 grid(6, 2 * Tc);
    gemm_xg<<<grid, 256, 0, stream>>>(x, Wih, bih, bhh, xg, t0, tcLog2);
    gru_mfma<<<BATCH / BB, 1024, 0, stream>>>(xg, Whh, bhh, hst, Tc);
  }
  fc_kernel<<<BATCH, 128, 0, stream>>>(hst, fcw, fcb, out);
}